// Round 1
// baseline (1148.782 us; speedup 1.0000x reference)
//
#include <hip/hip_runtime.h>
#include <cstdint>
#include <cstddef>

#define NNODES 50000
#define NEDGES 800000
#define INDIM  256
#define HD     128   // H*D
#define NH     4
#define NEG    0.2f

// ---- float <-> order-preserving unsigned (for atomicMax on float) ----
__device__ __forceinline__ unsigned f2ord(float f) {
    unsigned u = __float_as_uint(f);
    return (u & 0x80000000u) ? ~u : (u | 0x80000000u);
}
__device__ __forceinline__ float ord2f(unsigned u) {
    unsigned v = (u & 0x80000000u) ? (u ^ 0x80000000u) : ~u;
    return __uint_as_float(v);
}
// ord(-inf) = ~0xFF800000 = 0x007FFFFF
#define ORD_NEG_INF 0x007FFFFFu

// ---- init: zero out-features, zero denom, set m = ord(-inf) ----
__global__ void init_kernel(float* out_feat, float* denom, unsigned* mbuf,
                            int n_out, int n_nh) {
    int i = blockIdx.x * blockDim.x + threadIdx.x;
    if (i < n_out) out_feat[i] = 0.0f;
    if (i < n_nh) { denom[i] = 0.0f; mbuf[i] = ORD_NEG_INF; }
}

// ---- GEMM: el|er = h @ [W_src | W_dst] + [b_src | b_dst] ----
// 64x64 tile per block, 256 threads as 16x16, 4x4 microtile, K staged in 64-chunks.
__global__ __launch_bounds__(256) void gemm_kernel(
        const float* __restrict__ h,
        const float* __restrict__ Wsrc, const float* __restrict__ bsrc,
        const float* __restrict__ Wdst, const float* __restrict__ bdst,
        float* __restrict__ el, float* __restrict__ er) {
    __shared__ float hT[64 * 68];  // hT[k][r], stride 68 (16B-aligned rows)
    __shared__ float wS[64 * 68];  // wS[k][c]

    const int tid = threadIdx.x;
    const int tx = tid & 15, ty = tid >> 4;
    const int row0 = blockIdx.y * 64;
    const int c0g  = blockIdx.x * 64;   // global col in [0,256)

    float acc[4][4];
#pragma unroll
    for (int i = 0; i < 4; ++i)
#pragma unroll
        for (int j = 0; j < 4; ++j) acc[i][j] = 0.0f;

    for (int kk = 0; kk < INDIM; kk += 64) {
        // stage h tile (transposed): 64 rows x 64 k
#pragma unroll
        for (int i = 0; i < 16; ++i) {
            int idx = tid + i * 256;
            int r = idx >> 6, k = idx & 63;
            int grow = row0 + r;
            float v = (grow < NNODES) ? h[(size_t)grow * INDIM + kk + k] : 0.0f;
            hT[k * 68 + r] = v;
        }
        // stage W tile: 64 k x 64 cols (cols split between Wsrc/Wdst)
#pragma unroll
        for (int i = 0; i < 16; ++i) {
            int idx = tid + i * 256;
            int k = idx >> 6, c = idx & 63;
            int gc = c0g + c;
            float v = (gc < HD) ? Wsrc[(size_t)(kk + k) * HD + gc]
                                : Wdst[(size_t)(kk + k) * HD + (gc - HD)];
            wS[k * 68 + c] = v;
        }
        __syncthreads();
#pragma unroll 8
        for (int k = 0; k < 64; ++k) {
            const float4 av = *(const float4*)(&hT[k * 68 + ty * 4]);
            const float4 bv = *(const float4*)(&wS[k * 68 + tx * 4]);
            const float a0[4] = {av.x, av.y, av.z, av.w};
            const float b0[4] = {bv.x, bv.y, bv.z, bv.w};
#pragma unroll
            for (int i = 0; i < 4; ++i)
#pragma unroll
                for (int j = 0; j < 4; ++j) acc[i][j] += a0[i] * b0[j];
        }
        __syncthreads();
    }

#pragma unroll
    for (int i = 0; i < 4; ++i) {
        int row = row0 + ty * 4 + i;
        if (row >= NNODES) continue;
#pragma unroll
        for (int j = 0; j < 4; ++j) {
            int col = c0g + tx * 4 + j;
            float bias = (col < HD) ? bsrc[col] : bdst[col - HD];
            float v = acc[i][j] + bias;
            if (col < HD) el[(size_t)row * HD + col] = v;
            else          er[(size_t)row * HD + (col - HD)] = v;
        }
    }
}

// ---- Pass A: per-edge per-head scores + atomic segment max ----
// one wave (64 lanes) per edge; lane l owns feature dims 2l, 2l+1; head = l>>4
__global__ __launch_bounds__(256) void edge_scores_kernel(
        const float* __restrict__ el, const float* __restrict__ er,
        const int* __restrict__ src, const int* __restrict__ dst,
        const float* __restrict__ attn, float* __restrict__ scores,
        unsigned* __restrict__ mbuf) {
    int e = blockIdx.x * 4 + (threadIdx.x >> 6);
    if (e >= NEDGES) return;
    int lane = threadIdx.x & 63;
    int s = src[e], d = dst[e];

    const float2 ev = *(const float2*)(el + (size_t)s * HD + lane * 2);
    const float2 rv = *(const float2*)(er + (size_t)d * HD + lane * 2);
    float x0 = ev.x + rv.x; x0 = x0 > 0.0f ? x0 : NEG * x0;
    float x1 = ev.y + rv.y; x1 = x1 > 0.0f ? x1 : NEG * x1;
    float p = x0 * attn[lane * 2] + x1 * attn[lane * 2 + 1];

    // reduce within 16-lane groups (one head per group)
    p += __shfl_xor(p, 1, 16);
    p += __shfl_xor(p, 2, 16);
    p += __shfl_xor(p, 4, 16);
    p += __shfl_xor(p, 8, 16);

    if ((lane & 15) == 0) {
        int hh = lane >> 4;
        scores[(size_t)e * NH + hh] = p;
        atomicMax(mbuf + (size_t)d * NH + hh, f2ord(p));
    }
}

// ---- Pass B: ex = exp(score - m[dst]); denom += ex (in-place over scores) ----
__global__ __launch_bounds__(256) void edge_exp_kernel(
        const int* __restrict__ dst, float* __restrict__ scores,
        const unsigned* __restrict__ mbuf, float* __restrict__ denom) {
    int idx = blockIdx.x * blockDim.x + threadIdx.x;
    if (idx >= NEDGES * NH) return;
    int e = idx >> 2, hh = idx & 3;
    int d = dst[e];
    float m = ord2f(mbuf[(size_t)d * NH + hh]);
    float ex = expf(scores[idx] - m);
    scores[idx] = ex;
    atomicAdd(denom + (size_t)d * NH + hh, ex);
}

// ---- Pass C: a = ex/denom[dst]; out[dst] += a * el[src]; write a ----
__global__ __launch_bounds__(256) void edge_aggregate_kernel(
        const float* __restrict__ el,
        const int* __restrict__ src, const int* __restrict__ dst,
        const float* __restrict__ scores, const float* __restrict__ denom,
        float* __restrict__ out_feat, float* __restrict__ out_a) {
    int e = blockIdx.x * 4 + (threadIdx.x >> 6);
    if (e >= NEDGES) return;
    int lane = threadIdx.x & 63;
    int s = src[e], d = dst[e];
    int hh = lane >> 4;

    float ex  = scores[(size_t)e * NH + hh];
    float den = denom[(size_t)d * NH + hh];
    float aw  = ex / den;
    if ((lane & 15) == 0) out_a[(size_t)e * NH + hh] = aw;

    const float2 ev = *(const float2*)(el + (size_t)s * HD + lane * 2);
    atomicAdd(out_feat + (size_t)d * HD + lane * 2,     aw * ev.x);
    atomicAdd(out_feat + (size_t)d * HD + lane * 2 + 1, aw * ev.y);
}

extern "C" void kernel_launch(void* const* d_in, const int* in_sizes, int n_in,
                              void* d_out, int out_size, void* d_ws, size_t ws_size,
                              hipStream_t stream) {
    const float* h    = (const float*)d_in[0];
    const int*   src  = (const int*)d_in[1];
    const int*   dst  = (const int*)d_in[2];
    const float* Wsrc = (const float*)d_in[3];
    const float* bsrc = (const float*)d_in[4];
    const float* Wdst = (const float*)d_in[5];
    const float* bdst = (const float*)d_in[6];
    const float* attn = (const float*)d_in[7];

    float* out_feat = (float*)d_out;                       // N*128
    float* out_a    = out_feat + (size_t)NNODES * HD;      // E*4

    // workspace layout (floats)
    float*    el     = (float*)d_ws;                        // N*128
    float*    er     = el + (size_t)NNODES * HD;            // N*128
    float*    scores = er + (size_t)NNODES * HD;            // E*4 (later ex)
    unsigned* mbuf   = (unsigned*)(scores + (size_t)NEDGES * NH); // N*4
    float*    denom  = (float*)(mbuf + (size_t)NNODES * NH);      // N*4

    const int n_out = NNODES * HD;       // 6.4M
    const int n_nh  = NNODES * NH;       // 200K

    init_kernel<<<(n_out + 255) / 256, 256, 0, stream>>>(out_feat, denom, mbuf, n_out, n_nh);

    dim3 ggrid(256 / 64, (NNODES + 63) / 64);
    gemm_kernel<<<ggrid, 256, 0, stream>>>(h, Wsrc, bsrc, Wdst, bdst, el, er);

    edge_scores_kernel<<<(NEDGES + 3) / 4, 256, 0, stream>>>(el, er, src, dst, attn, scores, mbuf);

    edge_exp_kernel<<<(NEDGES * NH + 255) / 256, 256, 0, stream>>>(dst, scores, mbuf, denom);

    edge_aggregate_kernel<<<(NEDGES + 3) / 4, 256, 0, stream>>>(el, src, dst, scores, denom, out_feat, out_a);
}

// Round 2
// 788.984 us; speedup vs baseline: 1.4560x; 1.4560x over previous
//
#include <hip/hip_runtime.h>
#include <cstdint>
#include <cstddef>

#define NNODES 50000
#define NEDGES 800000
#define INDIM  256
#define HD     128   // H*D
#define NH     4
#define NEG    0.2f

// ================= GEMM: el|er = h @ [W_src|W_dst] + bias =================
// 64x64 tile per block, 256 threads as 16x16, 4x4 microtile, K staged in 64-chunks.
__global__ __launch_bounds__(256) void gemm_kernel(
        const float* __restrict__ h,
        const float* __restrict__ Wsrc, const float* __restrict__ bsrc,
        const float* __restrict__ Wdst, const float* __restrict__ bdst,
        float* __restrict__ el, float* __restrict__ er) {
    __shared__ float hT[64 * 68];  // hT[k][r]
    __shared__ float wS[64 * 68];  // wS[k][c]

    const int tid = threadIdx.x;
    const int tx = tid & 15, ty = tid >> 4;
    const int row0 = blockIdx.y * 64;
    const int c0g  = blockIdx.x * 64;   // global col in [0,256)

    float acc[4][4];
#pragma unroll
    for (int i = 0; i < 4; ++i)
#pragma unroll
        for (int j = 0; j < 4; ++j) acc[i][j] = 0.0f;

    for (int kk = 0; kk < INDIM; kk += 64) {
#pragma unroll
        for (int i = 0; i < 16; ++i) {
            int idx = tid + i * 256;
            int r = idx >> 6, k = idx & 63;
            int grow = row0 + r;
            float v = (grow < NNODES) ? h[(size_t)grow * INDIM + kk + k] : 0.0f;
            hT[k * 68 + r] = v;
        }
#pragma unroll
        for (int i = 0; i < 16; ++i) {
            int idx = tid + i * 256;
            int k = idx >> 6, c = idx & 63;
            int gc = c0g + c;
            float v = (gc < HD) ? Wsrc[(size_t)(kk + k) * HD + gc]
                                : Wdst[(size_t)(kk + k) * HD + (gc - HD)];
            wS[k * 68 + c] = v;
        }
        __syncthreads();
#pragma unroll 8
        for (int k = 0; k < 64; ++k) {
            const float4 av = *(const float4*)(&hT[k * 68 + ty * 4]);
            const float4 bv = *(const float4*)(&wS[k * 68 + tx * 4]);
            const float a0[4] = {av.x, av.y, av.z, av.w};
            const float b0[4] = {bv.x, bv.y, bv.z, bv.w};
#pragma unroll
            for (int i = 0; i < 4; ++i)
#pragma unroll
                for (int j = 0; j < 4; ++j) acc[i][j] += a0[i] * b0[j];
        }
        __syncthreads();
    }

#pragma unroll
    for (int i = 0; i < 4; ++i) {
        int row = row0 + ty * 4 + i;
        if (row >= NNODES) continue;
#pragma unroll
        for (int j = 0; j < 4; ++j) {
            int col = c0g + tx * 4 + j;
            float bias = (col < HD) ? bsrc[col] : bdst[col - HD];
            float v = acc[i][j] + bias;
            if (col < HD) el[(size_t)row * HD + col] = v;
            else          er[(size_t)row * HD + (col - HD)] = v;
        }
    }
}

// ================= CSR build =================
// cnt_work zeroed via hipMemsetAsync before this.
__global__ __launch_bounds__(256) void hist_kernel(
        const int* __restrict__ dst, int* __restrict__ cnt_work) {
    int e = blockIdx.x * blockDim.x + threadIdx.x;
    if (e < NEDGES) atomicAdd(cnt_work + dst[e], 1);
}

// single-block exclusive scan of 50000 counts -> rowptr[0..N], cnt_work := row starts
#define SCAN_T 1024
#define SCAN_CHUNK ((NNODES + SCAN_T - 1) / SCAN_T)
__global__ __launch_bounds__(SCAN_T) void scan_kernel(
        int* __restrict__ cnt_work, int* __restrict__ rowptr) {
    __shared__ int lds[SCAN_T];
    int t = threadIdx.x;
    int lo = t * SCAN_CHUNK;
    int hi = min(lo + SCAN_CHUNK, NNODES);
    int partial = 0;
    for (int i = lo; i < hi; ++i) partial += cnt_work[i];
    lds[t] = partial;
    __syncthreads();
    // Hillis-Steele inclusive scan
    for (int off = 1; off < SCAN_T; off <<= 1) {
        int v = (t >= off) ? lds[t - off] : 0;
        __syncthreads();
        lds[t] += v;
        __syncthreads();
    }
    int running = lds[t] - partial;  // exclusive prefix for this chunk
    for (int i = lo; i < hi; ++i) {
        int c = cnt_work[i];
        rowptr[i] = running;
        cnt_work[i] = running;   // scatter cursor = row start
        running += c;
    }
    if (t == SCAN_T - 1) rowptr[NNODES] = lds[SCAN_T - 1];
}

__global__ __launch_bounds__(256) void scatter_kernel(
        const int* __restrict__ dst, int* __restrict__ cnt_work,
        int* __restrict__ eidx) {
    int e = blockIdx.x * blockDim.x + threadIdx.x;
    if (e >= NEDGES) return;
    int pos = atomicAdd(cnt_work + dst[e], 1);
    eidx[pos] = e;
}

// ================= Pass A: raw per-edge per-head scores =================
// one wave per edge; lane l owns dims 2l,2l+1; head = l>>4. Writes scores into
// the out_a region (will be overwritten with normalized a by softmax pass).
__global__ __launch_bounds__(256) void edge_scores_kernel(
        const float* __restrict__ el, const float* __restrict__ er,
        const int* __restrict__ src, const int* __restrict__ dst,
        const float* __restrict__ attn, float* __restrict__ scores) {
    int e = blockIdx.x * 4 + (threadIdx.x >> 6);
    if (e >= NEDGES) return;
    int lane = threadIdx.x & 63;
    int s = src[e], d = dst[e];

    const float2 ev = *(const float2*)(el + (size_t)s * HD + lane * 2);
    const float2 rv = *(const float2*)(er + (size_t)d * HD + lane * 2);
    float x0 = ev.x + rv.x; x0 = x0 > 0.0f ? x0 : NEG * x0;
    float x1 = ev.y + rv.y; x1 = x1 > 0.0f ? x1 : NEG * x1;
    float p = x0 * attn[lane * 2] + x1 * attn[lane * 2 + 1];

    p += __shfl_xor(p, 1, 16);
    p += __shfl_xor(p, 2, 16);
    p += __shfl_xor(p, 4, 16);
    p += __shfl_xor(p, 8, 16);

    if ((lane & 15) == 0) scores[(size_t)e * NH + (lane >> 4)] = p;
}

// ================= Pass B: per-(node,head) softmax over CSR row =================
// reads raw scores from `a` (out_a region), overwrites with normalized weights
__global__ __launch_bounds__(256) void node_softmax_kernel(
        const int* __restrict__ rowptr, const int* __restrict__ eidx,
        float* __restrict__ a) {
    int idx = blockIdx.x * blockDim.x + threadIdx.x;
    if (idx >= NNODES * NH) return;
    int n = idx >> 2, hh = idx & 3;
    int lo = rowptr[n], hi = rowptr[n + 1];
    if (lo == hi) return;
    float m = -3.4e38f;
    for (int i = lo; i < hi; ++i) {
        float sc = a[(size_t)eidx[i] * NH + hh];
        m = fmaxf(m, sc);
    }
    float den = 0.0f;
    for (int i = lo; i < hi; ++i)
        den += expf(a[(size_t)eidx[i] * NH + hh] - m);
    float inv = 1.0f / den;
    for (int i = lo; i < hi; ++i) {
        size_t p = (size_t)eidx[i] * NH + hh;
        a[p] = expf(a[p] - m) * inv;
    }
}

// ================= Pass C: per-node wave aggregation (no atomics) =================
__global__ __launch_bounds__(256) void node_aggregate_kernel(
        const float* __restrict__ el, const int* __restrict__ src,
        const int* __restrict__ rowptr, const int* __restrict__ eidx,
        const float* __restrict__ a, float* __restrict__ out_feat) {
    int n = blockIdx.x * 4 + (threadIdx.x >> 6);
    if (n >= NNODES) return;
    int lane = threadIdx.x & 63;
    int hh = lane >> 4;
    int lo = rowptr[n], hi = rowptr[n + 1];

    float acc0 = 0.0f, acc1 = 0.0f;
    for (int i = lo; i < hi; ++i) {
        int e = eidx[i];
        int s = src[e];
        float aw = a[(size_t)e * NH + hh];
        const float2 ev = *(const float2*)(el + (size_t)s * HD + lane * 2);
        acc0 += aw * ev.x;
        acc1 += aw * ev.y;
    }
    float2 o; o.x = acc0; o.y = acc1;
    *(float2*)(out_feat + (size_t)n * HD + lane * 2) = o;
}

extern "C" void kernel_launch(void* const* d_in, const int* in_sizes, int n_in,
                              void* d_out, int out_size, void* d_ws, size_t ws_size,
                              hipStream_t stream) {
    const float* h    = (const float*)d_in[0];
    const int*   src  = (const int*)d_in[1];
    const int*   dst  = (const int*)d_in[2];
    const float* Wsrc = (const float*)d_in[3];
    const float* bsrc = (const float*)d_in[4];
    const float* Wdst = (const float*)d_in[5];
    const float* bdst = (const float*)d_in[6];
    const float* attn = (const float*)d_in[7];

    float* out_feat = (float*)d_out;                       // N*128
    float* out_a    = out_feat + (size_t)NNODES * HD;      // E*4 (scores, then a)

    // workspace layout
    float* el       = (float*)d_ws;                         // N*128 = 25.6 MB
    float* er       = el + (size_t)NNODES * HD;             // N*128 = 25.6 MB
    int*   cnt_work = (int*)(er + (size_t)NNODES * HD);     // N      (hist/cursor)
    int*   rowptr   = cnt_work + NNODES;                    // N+1
    int*   eidx     = rowptr + NNODES + 1;                  // E = 3.2 MB
    // total ws use ~54.8 MB

    // zero the histogram
    hipMemsetAsync(cnt_work, 0, NNODES * sizeof(int), stream);

    dim3 ggrid(256 / 64, (NNODES + 63) / 64);
    gemm_kernel<<<ggrid, 256, 0, stream>>>(h, Wsrc, bsrc, Wdst, bdst, el, er);

    hist_kernel<<<(NEDGES + 255) / 256, 256, 0, stream>>>(dst, cnt_work);
    scan_kernel<<<1, SCAN_T, 0, stream>>>(cnt_work, rowptr);
    scatter_kernel<<<(NEDGES + 255) / 256, 256, 0, stream>>>(dst, cnt_work, eidx);

    edge_scores_kernel<<<(NEDGES + 3) / 4, 256, 0, stream>>>(el, er, src, dst, attn, out_a);

    node_softmax_kernel<<<(NNODES * NH + 255) / 256, 256, 0, stream>>>(rowptr, eidx, out_a);

    node_aggregate_kernel<<<(NNODES + 3) / 4, 256, 0, stream>>>(
        el, src, rowptr, eidx, out_a, out_feat);
}

// Round 3
// 500.471 us; speedup vs baseline: 2.2954x; 1.5765x over previous
//
#include <hip/hip_runtime.h>
#include <cstdint>
#include <cstddef>

#define NNODES 50000
#define NEDGES 800000
#define INDIM  256
#define HD     128   // H*D
#define NH     4
#define NEG    0.2f

typedef __attribute__((ext_vector_type(8))) short   short8;   // 8 bf16 (4 VGPRs)
typedef __attribute__((ext_vector_type(8))) ushort  ushort8;
typedef __attribute__((ext_vector_type(4))) float   floatx4;

// f32 -> bf16 (round-to-nearest-even), as raw ushort bits
__device__ __forceinline__ ushort f2bf(float f) {
    unsigned u = __float_as_uint(f);
    unsigned r = u + 0x7fffu + ((u >> 16) & 1u);
    return (ushort)(r >> 16);
}

// ================= W convert+transpose: Wt[n][k] bf16, n in [0,256) =================
__global__ __launch_bounds__(256) void conv_w_kernel(
        const float* __restrict__ Wsrc, const float* __restrict__ Wdst,
        ushort* __restrict__ Wt) {
    int idx = blockIdx.x * 256 + threadIdx.x;   // 65536 total
    if (idx >= 2 * HD * INDIM) return;
    int n = idx >> 8, k = idx & 255;
    float v = (n < HD) ? Wsrc[(size_t)k * HD + n] : Wdst[(size_t)k * HD + (n - HD)];
    Wt[idx] = f2bf(v);
}

// ================= MFMA GEMM: el|er = h @ [W_src|W_dst] + bias =================
// block = 128 rows x 128 cols (grid.x in {0,1}: 0 -> el cols, 1 -> er cols)
// 4 waves; wave w covers rows w*32..w*32+31 (2 m-tiles) x all 8 n-tiles.
__global__ __launch_bounds__(256) void gemm_mfma_kernel(
        const float* __restrict__ h, const ushort* __restrict__ Wt,
        const float* __restrict__ bsrc, const float* __restrict__ bdst,
        float* __restrict__ el, float* __restrict__ er) {
    __shared__ ushort As[128 * 32];  // As[r][k] bf16
    __shared__ ushort Bs[128 * 32];  // Bs[n][k] bf16 (Wt rows)

    const int tid  = threadIdx.x;
    const int wave = tid >> 6, lane = tid & 63;
    const int row0 = blockIdx.y * 128;
    const int col0 = blockIdx.x * 128;   // 0 -> el, 128 -> er
    const int l15  = lane & 15, quad = lane >> 4;

    floatx4 acc[2][8];
#pragma unroll
    for (int i = 0; i < 2; ++i)
#pragma unroll
        for (int j = 0; j < 8; ++j) acc[i][j] = (floatx4){0.f, 0.f, 0.f, 0.f};

    for (int kk = 0; kk < INDIM; kk += 32) {
        // stage A (convert f32->bf16) and B (already bf16): 512 chunks of 8 elems each
#pragma unroll
        for (int it = 0; it < 2; ++it) {
            int c = tid + it * 256;
            int r = c >> 2;            // 0..127
            int off = (c & 3) * 8;     // 0,8,16,24
            // ---- A ----
            int grow = row0 + r;
            ushort8 aw;
            if (grow < NNODES) {
                const float* hp = h + (size_t)grow * INDIM + kk + off;
                float4 v0 = *(const float4*)(hp);
                float4 v1 = *(const float4*)(hp + 4);
                aw[0] = f2bf(v0.x); aw[1] = f2bf(v0.y); aw[2] = f2bf(v0.z); aw[3] = f2bf(v0.w);
                aw[4] = f2bf(v1.x); aw[5] = f2bf(v1.y); aw[6] = f2bf(v1.z); aw[7] = f2bf(v1.w);
            } else {
                aw = (ushort8){0,0,0,0,0,0,0,0};
            }
            *(ushort8*)(As + r * 32 + off) = aw;
            // ---- B ----
            ushort8 bw = *(const ushort8*)(Wt + (size_t)(col0 + r) * INDIM + kk + off);
            *(ushort8*)(Bs + r * 32 + off) = bw;
        }
        __syncthreads();

        short8 af[2], bf[8];
#pragma unroll
        for (int tm = 0; tm < 2; ++tm)
            af[tm] = *(const short8*)(As + (wave * 32 + tm * 16 + l15) * 32 + quad * 8);
#pragma unroll
        for (int tn = 0; tn < 8; ++tn)
            bf[tn] = *(const short8*)(Bs + (tn * 16 + l15) * 32 + quad * 8);
#pragma unroll
        for (int tm = 0; tm < 2; ++tm)
#pragma unroll
            for (int tn = 0; tn < 8; ++tn)
                acc[tm][tn] = __builtin_amdgcn_mfma_f32_16x16x32_bf16(
                    af[tm], bf[tn], acc[tm][tn], 0, 0, 0);
        __syncthreads();
    }

    // epilogue: C/D layout col=lane&15, row=quad*4+reg
    float* outp = (col0 == 0) ? el : er;
    const float* biasp = (col0 == 0) ? bsrc : bdst;
#pragma unroll
    for (int tn = 0; tn < 8; ++tn) {
        int col = tn * 16 + l15;
        float bias = biasp[col];
#pragma unroll
        for (int tm = 0; tm < 2; ++tm) {
#pragma unroll
            for (int reg = 0; reg < 4; ++reg) {
                int row = row0 + wave * 32 + tm * 16 + quad * 4 + reg;
                if (row < NNODES)
                    outp[(size_t)row * HD + col] = acc[tm][tn][reg] + bias;
            }
        }
    }
}

// ================= CSR build =================
__global__ __launch_bounds__(256) void hist_kernel(
        const int* __restrict__ dst, int* __restrict__ cnt_work) {
    int e = blockIdx.x * blockDim.x + threadIdx.x;
    if (e < NEDGES) atomicAdd(cnt_work + dst[e], 1);
}

#define SCAN_T 1024
#define SCAN_CHUNK ((NNODES + SCAN_T - 1) / SCAN_T)
__global__ __launch_bounds__(SCAN_T) void scan_kernel(
        int* __restrict__ cnt_work, int* __restrict__ rowptr) {
    __shared__ int lds[SCAN_T];
    int t = threadIdx.x;
    int lo = t * SCAN_CHUNK;
    int hi = min(lo + SCAN_CHUNK, NNODES);
    int partial = 0;
    for (int i = lo; i < hi; ++i) partial += cnt_work[i];
    lds[t] = partial;
    __syncthreads();
    for (int off = 1; off < SCAN_T; off <<= 1) {
        int v = (t >= off) ? lds[t - off] : 0;
        __syncthreads();
        lds[t] += v;
        __syncthreads();
    }
    int running = lds[t] - partial;
    for (int i = lo; i < hi; ++i) {
        int c = cnt_work[i];
        rowptr[i] = running;
        cnt_work[i] = running;
        running += c;
    }
    if (t == SCAN_T - 1) rowptr[NNODES] = lds[SCAN_T - 1];
}

__global__ __launch_bounds__(256) void scatter_kernel(
        const int* __restrict__ dst, int* __restrict__ cnt_work,
        int* __restrict__ eidx) {
    int e = blockIdx.x * blockDim.x + threadIdx.x;
    if (e >= NEDGES) return;
    int pos = atomicAdd(cnt_work + dst[e], 1);
    eidx[pos] = e;
}

// ================= fused: scores + online softmax + aggregate, per-node wave =================
// lane l owns dims 2l,2l+1; head hh = l>>4 (16 lanes per head = dims 32h..32h+31)
__global__ __launch_bounds__(256) void node_fused_kernel(
        const float* __restrict__ el, const float* __restrict__ er,
        const int* __restrict__ src,
        const int* __restrict__ rowptr, const int* __restrict__ eidx,
        const float* __restrict__ attn,
        float* __restrict__ scores_raw,   // = out_a region, raw scores
        float* __restrict__ mbuf, float* __restrict__ lbuf,
        float* __restrict__ out_feat) {
    int n = blockIdx.x * 4 + (threadIdx.x >> 6);
    if (n >= NNODES) return;
    int lane = threadIdx.x & 63;
    int hh = lane >> 4;
    int lo = rowptr[n], hi = rowptr[n + 1];

    const float2 rv = *(const float2*)(er + (size_t)n * HD + lane * 2);
    const float a0 = attn[lane * 2], a1 = attn[lane * 2 + 1];

    float m = -3.4e38f, lsum = 0.0f, acc0 = 0.0f, acc1 = 0.0f;
    for (int i = lo; i < hi; ++i) {
        int e = eidx[i];
        int s = src[e];
        const float2 ev = *(const float2*)(el + (size_t)s * HD + lane * 2);
        float x0 = ev.x + rv.x; x0 = x0 > 0.0f ? x0 : NEG * x0;
        float x1 = ev.y + rv.y; x1 = x1 > 0.0f ? x1 : NEG * x1;
        float p = x0 * a0 + x1 * a1;
        p += __shfl_xor(p, 1, 16);
        p += __shfl_xor(p, 2, 16);
        p += __shfl_xor(p, 4, 16);
        p += __shfl_xor(p, 8, 16);
        if ((lane & 15) == 0) scores_raw[(size_t)e * NH + hh] = p;
        float mn = fmaxf(m, p);
        float scale = __expf(m - mn);
        float w = __expf(p - mn);
        lsum = lsum * scale + w;
        acc0 = acc0 * scale + w * ev.x;
        acc1 = acc1 * scale + w * ev.y;
        m = mn;
    }
    float2 o;
    if (lo == hi) {
        o.x = 0.0f; o.y = 0.0f;
    } else {
        float inv = 1.0f / lsum;
        o.x = acc0 * inv; o.y = acc1 * inv;
    }
    *(float2*)(out_feat + (size_t)n * HD + lane * 2) = o;
    if ((lane & 15) == 0) {
        mbuf[n * NH + hh] = m;
        lbuf[n * NH + hh] = lsum;
    }
}

// ================= normalize attention weights in place =================
__global__ __launch_bounds__(256) void edge_attn_kernel(
        const int* __restrict__ dst, float* __restrict__ a,
        const float* __restrict__ mbuf, const float* __restrict__ lbuf) {
    int idx = blockIdx.x * blockDim.x + threadIdx.x;
    if (idx >= NEDGES * NH) return;
    int e = idx >> 2, hh = idx & 3;
    int d = dst[e];
    a[idx] = __expf(a[idx] - mbuf[d * NH + hh]) / lbuf[d * NH + hh];
}

extern "C" void kernel_launch(void* const* d_in, const int* in_sizes, int n_in,
                              void* d_out, int out_size, void* d_ws, size_t ws_size,
                              hipStream_t stream) {
    const float* h    = (const float*)d_in[0];
    const int*   src  = (const int*)d_in[1];
    const int*   dst  = (const int*)d_in[2];
    const float* Wsrc = (const float*)d_in[3];
    const float* bsrc = (const float*)d_in[4];
    const float* Wdst = (const float*)d_in[5];
    const float* bdst = (const float*)d_in[6];
    const float* attn = (const float*)d_in[7];

    float* out_feat = (float*)d_out;                       // N*128
    float* out_a    = out_feat + (size_t)NNODES * HD;      // E*4 (raw scores, then a)

    // workspace layout (16B-aligned chunks)
    float*  el       = (float*)d_ws;                        // N*128
    float*  er       = el + (size_t)NNODES * HD;            // N*128
    float*  mbuf     = er + (size_t)NNODES * HD;            // N*4
    float*  lbuf     = mbuf + (size_t)NNODES * NH;          // N*4
    ushort* Wt       = (ushort*)(lbuf + (size_t)NNODES * NH); // 256*256 bf16
    int*    cnt_work = (int*)(Wt + 2 * HD * INDIM);         // N
    int*    rowptr   = cnt_work + NNODES;                   // N+1
    int*    eidx     = rowptr + NNODES + 1;                 // E

    hipMemsetAsync(cnt_work, 0, NNODES * sizeof(int), stream);

    conv_w_kernel<<<(2 * HD * INDIM + 255) / 256, 256, 0, stream>>>(Wsrc, Wdst, Wt);

    dim3 ggrid(2, (NNODES + 127) / 128);
    gemm_mfma_kernel<<<ggrid, 256, 0, stream>>>(h, Wt, bsrc, bdst, el, er);

    hist_kernel<<<(NEDGES + 255) / 256, 256, 0, stream>>>(dst, cnt_work);
    scan_kernel<<<1, SCAN_T, 0, stream>>>(cnt_work, rowptr);
    scatter_kernel<<<(NEDGES + 255) / 256, 256, 0, stream>>>(dst, cnt_work, eidx);

    node_fused_kernel<<<(NNODES + 3) / 4, 256, 0, stream>>>(
        el, er, src, rowptr, eidx, attn, out_a, mbuf, lbuf, out_feat);

    edge_attn_kernel<<<(NEDGES * NH + 255) / 256, 256, 0, stream>>>(dst, out_a, mbuf, lbuf);
}

// Round 4
// 484.086 us; speedup vs baseline: 2.3731x; 1.0338x over previous
//
#include <hip/hip_runtime.h>
#include <cstdint>
#include <cstddef>

#define NNODES 50000
#define NEDGES 800000
#define INDIM  256
#define HD     128   // H*D
#define NH     4
#define NEG    0.2f

typedef __attribute__((ext_vector_type(8))) short   short8;   // 8 bf16 (4 VGPRs)
typedef __attribute__((ext_vector_type(8))) ushort  ushort8;
typedef __attribute__((ext_vector_type(4))) float   floatx4;

// f32 -> bf16 (round-to-nearest-even), raw bits
__device__ __forceinline__ ushort f2bf(float f) {
    unsigned u = __float_as_uint(f);
    unsigned r = u + 0x7fffu + ((u >> 16) & 1u);
    return (ushort)(r >> 16);
}
__device__ __forceinline__ float bf2f(ushort u) {
    return __uint_as_float(((unsigned)u) << 16);
}

// ================= W convert+transpose (LDS-tiled): Wt[n][k] bf16 =================
// grid (INDIM/32, 256/32), block (32,8)
__global__ __launch_bounds__(256) void conv_w_kernel(
        const float* __restrict__ Wsrc, const float* __restrict__ Wdst,
        ushort* __restrict__ Wt) {
    __shared__ float t[32][33];
    int kb = blockIdx.x * 32, nb = blockIdx.y * 32;
    for (int i = threadIdx.y; i < 32; i += 8) {
        int k = kb + i, n = nb + threadIdx.x;
        float v = (n < HD) ? Wsrc[(size_t)k * HD + n] : Wdst[(size_t)k * HD + (n - HD)];
        t[i][threadIdx.x] = v;
    }
    __syncthreads();
    for (int i = threadIdx.y; i < 32; i += 8) {
        int n = nb + i, k = kb + threadIdx.x;
        Wt[(size_t)n * INDIM + k] = f2bf(t[threadIdx.x][i]);
    }
}

// LDS chunk swizzle: chunk = fragment (16 rows x 8 k) id, conflict-free both ways
__device__ __forceinline__ int swz(int c) { return c ^ ((c >> 4) & 7); }

// ================= MFMA GEMM =================
// grid.x==0 -> el (bf16 out), grid.x==1 -> er (f32 out). 128 rows x 128 cols per block.
__global__ __launch_bounds__(256) void gemm_mfma_kernel(
        const float* __restrict__ h, const ushort* __restrict__ Wt,
        const float* __restrict__ bsrc, const float* __restrict__ bdst,
        ushort* __restrict__ el_bf, float* __restrict__ er) {
    __shared__ ushort As[512 * 8];  // 512 fragment-chunks of 8 bf16
    __shared__ ushort Bs[512 * 8];

    const int tid  = threadIdx.x;
    const int wave = tid >> 6, lane = tid & 63;
    const int row0 = blockIdx.y * 128;
    const int col0 = blockIdx.x * 128;   // 0 -> el, 128 -> er
    const int l15  = lane & 15, quad = lane >> 4;

    floatx4 acc[2][8];
#pragma unroll
    for (int i = 0; i < 2; ++i)
#pragma unroll
        for (int j = 0; j < 8; ++j) acc[i][j] = (floatx4){0.f, 0.f, 0.f, 0.f};

    for (int kk = 0; kk < INDIM; kk += 32) {
#pragma unroll
        for (int it = 0; it < 2; ++it) {
            int idx = tid + it * 256;    // 0..511
            int r = idx >> 2;            // 0..127
            int kq = idx & 3;            // k-quad (8 elems)
            int c = (r >> 4) * 64 + kq * 16 + (r & 15);
            // ---- A: convert f32 -> bf16 ----
            int grow = row0 + r;
            ushort8 aw;
            if (grow < NNODES) {
                const float* hp = h + (size_t)grow * INDIM + kk + kq * 8;
                float4 v0 = *(const float4*)(hp);
                float4 v1 = *(const float4*)(hp + 4);
                aw[0] = f2bf(v0.x); aw[1] = f2bf(v0.y); aw[2] = f2bf(v0.z); aw[3] = f2bf(v0.w);
                aw[4] = f2bf(v1.x); aw[5] = f2bf(v1.y); aw[6] = f2bf(v1.z); aw[7] = f2bf(v1.w);
            } else {
                aw = (ushort8){0,0,0,0,0,0,0,0};
            }
            *(ushort8*)(As + swz(c) * 8) = aw;
            // ---- B: already bf16 ----
            ushort8 bw = *(const ushort8*)(Wt + (size_t)(col0 + r) * INDIM + kk + kq * 8);
            *(ushort8*)(Bs + swz(c) * 8) = bw;
        }
        __syncthreads();

        short8 af[2], bf[8];
#pragma unroll
        for (int tm = 0; tm < 2; ++tm) {
            int c = (wave * 2 + tm) * 64 + quad * 16 + l15;
            af[tm] = *(const short8*)(As + swz(c) * 8);
        }
#pragma unroll
        for (int tn = 0; tn < 8; ++tn) {
            int c = tn * 64 + quad * 16 + l15;
            bf[tn] = *(const short8*)(Bs + swz(c) * 8);
        }
#pragma unroll
        for (int tm = 0; tm < 2; ++tm)
#pragma unroll
            for (int tn = 0; tn < 8; ++tn)
                acc[tm][tn] = __builtin_amdgcn_mfma_f32_16x16x32_bf16(
                    af[tm], bf[tn], acc[tm][tn], 0, 0, 0);
        __syncthreads();
    }

    // epilogue: C/D layout col=lane&15, row=quad*4+reg
    if (col0 == 0) {
#pragma unroll
        for (int tn = 0; tn < 8; ++tn) {
            int col = tn * 16 + l15;
            float bias = bsrc[col];
#pragma unroll
            for (int tm = 0; tm < 2; ++tm)
#pragma unroll
                for (int reg = 0; reg < 4; ++reg) {
                    int row = row0 + wave * 32 + tm * 16 + quad * 4 + reg;
                    if (row < NNODES)
                        el_bf[(size_t)row * HD + col] = f2bf(acc[tm][tn][reg] + bias);
                }
        }
    } else {
#pragma unroll
        for (int tn = 0; tn < 8; ++tn) {
            int col = tn * 16 + l15;
            float bias = bdst[col];
#pragma unroll
            for (int tm = 0; tm < 2; ++tm)
#pragma unroll
                for (int reg = 0; reg < 4; ++reg) {
                    int row = row0 + wave * 32 + tm * 16 + quad * 4 + reg;
                    if (row < NNODES)
                        er[(size_t)row * HD + col] = acc[tm][tn][reg] + bias;
                }
        }
    }
}

// ================= CSR build =================
__global__ __launch_bounds__(256) void hist_kernel(
        const int* __restrict__ dst, int* __restrict__ cnt_work) {
    int e = blockIdx.x * blockDim.x + threadIdx.x;
    if (e < NEDGES) atomicAdd(cnt_work + dst[e], 1);
}

#define SCAN_T 1024
#define SCAN_CHUNK ((NNODES + SCAN_T - 1) / SCAN_T)
__global__ __launch_bounds__(SCAN_T) void scan_kernel(
        int* __restrict__ cnt_work, int* __restrict__ rowptr) {
    __shared__ int lds[SCAN_T];
    int t = threadIdx.x;
    int lo = t * SCAN_CHUNK;
    int hi = min(lo + SCAN_CHUNK, NNODES);
    int partial = 0;
    for (int i = lo; i < hi; ++i) partial += cnt_work[i];
    lds[t] = partial;
    __syncthreads();
    for (int off = 1; off < SCAN_T; off <<= 1) {
        int v = (t >= off) ? lds[t - off] : 0;
        __syncthreads();
        lds[t] += v;
        __syncthreads();
    }
    int running = lds[t] - partial;
    for (int i = lo; i < hi; ++i) {
        int c = cnt_work[i];
        rowptr[i] = running;
        cnt_work[i] = running;
        running += c;
    }
    if (t == SCAN_T - 1) rowptr[NNODES] = lds[SCAN_T - 1];
}

__global__ __launch_bounds__(256) void scatter_kernel(
        const int* __restrict__ src, const int* __restrict__ dst,
        int* __restrict__ cnt_work,
        int* __restrict__ eidx, int* __restrict__ esrc) {
    int e = blockIdx.x * blockDim.x + threadIdx.x;
    if (e >= NEDGES) return;
    int s = src[e];
    int pos = atomicAdd(cnt_work + dst[e], 1);
    eidx[pos] = e;
    esrc[pos] = s;
}

// ================= fused: scores + online softmax + aggregate, per-node wave =================
__global__ __launch_bounds__(256) void node_fused_kernel(
        const ushort* __restrict__ el_bf, const float* __restrict__ er,
        const int* __restrict__ rowptr, const int* __restrict__ eidx,
        const int* __restrict__ esrc,
        const float* __restrict__ attn,
        float* __restrict__ scores_raw,   // = out_a region, raw scores
        float* __restrict__ mbuf, float* __restrict__ lbuf,
        float* __restrict__ out_feat) {
    int n = blockIdx.x * 4 + (threadIdx.x >> 6);
    if (n >= NNODES) return;
    int lane = threadIdx.x & 63;
    int hh = lane >> 4;
    int lo = rowptr[n], hi = rowptr[n + 1];

    const float2 rv = *(const float2*)(er + (size_t)n * HD + lane * 2);
    const float a0 = attn[lane * 2], a1 = attn[lane * 2 + 1];

    float m = -3.4e38f, lsum = 0.0f, acc0 = 0.0f, acc1 = 0.0f;

    // software pipeline: el gather one edge ahead
    ushort2 u;
    if (lo < hi) {
        int s0 = esrc[lo];
        u = *(const ushort2*)(el_bf + (size_t)s0 * HD + lane * 2);
    }
    for (int i = lo; i < hi; ++i) {
        float evx = bf2f(u.x), evy = bf2f(u.y);
        if (i + 1 < hi) {
            int s1 = esrc[i + 1];
            u = *(const ushort2*)(el_bf + (size_t)s1 * HD + lane * 2);
        }
        int e = eidx[i];
        float x0 = evx + rv.x; x0 = x0 > 0.0f ? x0 : NEG * x0;
        float x1 = evy + rv.y; x1 = x1 > 0.0f ? x1 : NEG * x1;
        float p = x0 * a0 + x1 * a1;
        p += __shfl_xor(p, 1, 16);
        p += __shfl_xor(p, 2, 16);
        p += __shfl_xor(p, 4, 16);
        p += __shfl_xor(p, 8, 16);
        if ((lane & 15) == 0) scores_raw[(size_t)e * NH + hh] = p;
        float mn = fmaxf(m, p);
        float scale = __expf(m - mn);
        float w = __expf(p - mn);
        lsum = lsum * scale + w;
        acc0 = acc0 * scale + w * evx;
        acc1 = acc1 * scale + w * evy;
        m = mn;
    }
    float2 o;
    if (lo == hi) {
        o.x = 0.0f; o.y = 0.0f;
    } else {
        float inv = 1.0f / lsum;
        o.x = acc0 * inv; o.y = acc1 * inv;
    }
    *(float2*)(out_feat + (size_t)n * HD + lane * 2) = o;
    if ((lane & 15) == 0) {
        mbuf[n * NH + hh] = m;
        lbuf[n * NH + hh] = lsum;
    }
}

// ================= normalize attention weights in place =================
__global__ __launch_bounds__(256) void edge_attn_kernel(
        const int* __restrict__ dst, float* __restrict__ a,
        const float* __restrict__ mbuf, const float* __restrict__ lbuf) {
    int idx = blockIdx.x * blockDim.x + threadIdx.x;
    if (idx >= NEDGES * NH) return;
    int e = idx >> 2, hh = idx & 3;
    int d = dst[e];
    a[idx] = __expf(a[idx] - mbuf[d * NH + hh]) / lbuf[d * NH + hh];
}

extern "C" void kernel_launch(void* const* d_in, const int* in_sizes, int n_in,
                              void* d_out, int out_size, void* d_ws, size_t ws_size,
                              hipStream_t stream) {
    const float* h    = (const float*)d_in[0];
    const int*   src  = (const int*)d_in[1];
    const int*   dst  = (const int*)d_in[2];
    const float* Wsrc = (const float*)d_in[3];
    const float* bsrc = (const float*)d_in[4];
    const float* Wdst = (const float*)d_in[5];
    const float* bdst = (const float*)d_in[6];
    const float* attn = (const float*)d_in[7];

    float* out_feat = (float*)d_out;                       // N*128
    float* out_a    = out_feat + (size_t)NNODES * HD;      // E*4 (raw scores, then a)

    // workspace layout (each segment 16B-aligned)
    float*  er       = (float*)d_ws;                         // N*128 f32
    float*  mbuf     = er + (size_t)NNODES * HD;             // N*4
    float*  lbuf     = mbuf + (size_t)NNODES * NH;           // N*4
    ushort* Wt       = (ushort*)(lbuf + (size_t)NNODES * NH);// 256*256 bf16
    ushort* el_bf    = Wt + 2 * HD * INDIM;                  // N*128 bf16
    int*    cnt_work = (int*)(el_bf + (size_t)NNODES * HD);  // N
    int*    eidx     = cnt_work + NNODES;                    // E
    int*    esrc     = eidx + NEDGES;                        // E
    int*    rowptr   = esrc + NEDGES;                        // N+1

    hipMemsetAsync(cnt_work, 0, NNODES * sizeof(int), stream);

    dim3 cwgrid(INDIM / 32, 256 / 32);
    conv_w_kernel<<<cwgrid, dim3(32, 8), 0, stream>>>(Wsrc, Wdst, Wt);

    dim3 ggrid(2, (NNODES + 127) / 128);
    gemm_mfma_kernel<<<ggrid, 256, 0, stream>>>(h, Wt, bsrc, bdst, el_bf, er);

    hist_kernel<<<(NEDGES + 255) / 256, 256, 0, stream>>>(dst, cnt_work);
    scan_kernel<<<1, SCAN_T, 0, stream>>>(cnt_work, rowptr);
    scatter_kernel<<<(NEDGES + 255) / 256, 256, 0, stream>>>(src, dst, cnt_work, eidx, esrc);

    node_fused_kernel<<<(NNODES + 3) / 4, 256, 0, stream>>>(
        el_bf, er, rowptr, eidx, esrc, attn, out_a, mbuf, lbuf, out_feat);

    edge_attn_kernel<<<(NEDGES * NH + 255) / 256, 256, 0, stream>>>(dst, out_a, mbuf, lbuf);
}

// Round 5
// 421.942 us; speedup vs baseline: 2.7226x; 1.1473x over previous
//
#include <hip/hip_runtime.h>
#include <cstdint>
#include <cstddef>

#define NNODES 50000
#define NEDGES 800000
#define INDIM  256
#define HD     128   // H*D
#define NH     4
#define NEG    0.2f

typedef __attribute__((ext_vector_type(8))) short   short8;   // 8 bf16 (4 VGPRs)
typedef __attribute__((ext_vector_type(8))) ushort  ushort8;
typedef __attribute__((ext_vector_type(4))) float   floatx4;

// f32 -> bf16 (round-to-nearest-even), raw bits
__device__ __forceinline__ ushort f2bf(float f) {
    unsigned u = __float_as_uint(f);
    unsigned r = u + 0x7fffu + ((u >> 16) & 1u);
    return (ushort)(r >> 16);
}
__device__ __forceinline__ float bf2f(ushort u) {
    return __uint_as_float(((unsigned)u) << 16);
}

// ================= h convert: f32 -> bf16, 8 elems/thread =================
__global__ __launch_bounds__(256) void conv_h_kernel(
        const float* __restrict__ h, ushort* __restrict__ h_bf) {
    int idx = blockIdx.x * 256 + threadIdx.x;     // chunk of 8
    const int total = NNODES * INDIM / 8;         // 1.6M
    if (idx >= total) return;
    const float* p = h + (size_t)idx * 8;
    float4 v0 = *(const float4*)p;
    float4 v1 = *(const float4*)(p + 4);
    ushort8 o;
    o[0] = f2bf(v0.x); o[1] = f2bf(v0.y); o[2] = f2bf(v0.z); o[3] = f2bf(v0.w);
    o[4] = f2bf(v1.x); o[5] = f2bf(v1.y); o[6] = f2bf(v1.z); o[7] = f2bf(v1.w);
    *(ushort8*)(h_bf + (size_t)idx * 8) = o;
}

// ================= W convert+transpose (LDS-tiled): Wt[n][k] bf16 =================
__global__ __launch_bounds__(256) void conv_w_kernel(
        const float* __restrict__ Wsrc, const float* __restrict__ Wdst,
        ushort* __restrict__ Wt) {
    __shared__ float t[32][33];
    int kb = blockIdx.x * 32, nb = blockIdx.y * 32;
    for (int i = threadIdx.y; i < 32; i += 8) {
        int k = kb + i, n = nb + threadIdx.x;
        float v = (n < HD) ? Wsrc[(size_t)k * HD + n] : Wdst[(size_t)k * HD + (n - HD)];
        t[i][threadIdx.x] = v;
    }
    __syncthreads();
    for (int i = threadIdx.y; i < 32; i += 8) {
        int n = nb + i, k = kb + threadIdx.x;
        Wt[(size_t)n * INDIM + k] = f2bf(t[threadIdx.x][i]);
    }
}

// LDS chunk swizzle: conflict-free staging writes + fragment reads
__device__ __forceinline__ int swz(int c) { return c ^ ((c >> 4) & 7); }

// ================= MFMA GEMM =================
// grid.x==0 -> el (bf16 out), grid.x==1 -> er (f32 out). 128 rows x 128 cols per block.
__global__ __launch_bounds__(256) void gemm_mfma_kernel(
        const ushort* __restrict__ h_bf, const ushort* __restrict__ Wt,
        const float* __restrict__ bsrc, const float* __restrict__ bdst,
        ushort* __restrict__ el_bf, float* __restrict__ er) {
    __shared__ ushort As[512 * 8];  // 512 fragment-chunks of 8 bf16
    __shared__ ushort Bs[512 * 8];

    const int tid  = threadIdx.x;
    const int wave = tid >> 6, lane = tid & 63;
    const int row0 = blockIdx.y * 128;
    const int col0 = blockIdx.x * 128;   // 0 -> el, 128 -> er
    const int l15  = lane & 15, quad = lane >> 4;

    floatx4 acc[2][8];
#pragma unroll
    for (int i = 0; i < 2; ++i)
#pragma unroll
        for (int j = 0; j < 8; ++j) acc[i][j] = (floatx4){0.f, 0.f, 0.f, 0.f};

    for (int kk = 0; kk < INDIM; kk += 32) {
#pragma unroll
        for (int it = 0; it < 2; ++it) {
            int idx = tid + it * 256;    // 0..511
            int r = idx >> 2;            // 0..127
            int kq = idx & 3;            // k-quad (8 elems)
            int c = (r >> 4) * 64 + kq * 16 + (r & 15);
            // ---- A: pre-converted bf16 ----
            int grow = row0 + r;
            ushort8 aw = (ushort8){0,0,0,0,0,0,0,0};
            if (grow < NNODES)
                aw = *(const ushort8*)(h_bf + (size_t)grow * INDIM + kk + kq * 8);
            *(ushort8*)(As + swz(c) * 8) = aw;
            // ---- B ----
            ushort8 bw = *(const ushort8*)(Wt + (size_t)(col0 + r) * INDIM + kk + kq * 8);
            *(ushort8*)(Bs + swz(c) * 8) = bw;
        }
        __syncthreads();

        short8 af[2], bf[8];
#pragma unroll
        for (int tm = 0; tm < 2; ++tm) {
            int c = (wave * 2 + tm) * 64 + quad * 16 + l15;
            af[tm] = *(const short8*)(As + swz(c) * 8);
        }
#pragma unroll
        for (int tn = 0; tn < 8; ++tn) {
            int c = tn * 64 + quad * 16 + l15;
            bf[tn] = *(const short8*)(Bs + swz(c) * 8);
        }
#pragma unroll
        for (int tm = 0; tm < 2; ++tm)
#pragma unroll
            for (int tn = 0; tn < 8; ++tn)
                acc[tm][tn] = __builtin_amdgcn_mfma_f32_16x16x32_bf16(
                    af[tm], bf[tn], acc[tm][tn], 0, 0, 0);
        __syncthreads();
    }

    // epilogue: C/D layout col=lane&15, row=quad*4+reg
    if (col0 == 0) {
#pragma unroll
        for (int tn = 0; tn < 8; ++tn) {
            int col = tn * 16 + l15;
            float bias = bsrc[col];
#pragma unroll
            for (int tm = 0; tm < 2; ++tm)
#pragma unroll
                for (int reg = 0; reg < 4; ++reg) {
                    int row = row0 + wave * 32 + tm * 16 + quad * 4 + reg;
                    if (row < NNODES)
                        el_bf[(size_t)row * HD + col] = f2bf(acc[tm][tn][reg] + bias);
                }
        }
    } else {
#pragma unroll
        for (int tn = 0; tn < 8; ++tn) {
            int col = tn * 16 + l15;
            float bias = bdst[col];
#pragma unroll
            for (int tm = 0; tm < 2; ++tm)
#pragma unroll
                for (int reg = 0; reg < 4; ++reg) {
                    int row = row0 + wave * 32 + tm * 16 + quad * 4 + reg;
                    if (row < NNODES)
                        er[(size_t)row * HD + col] = acc[tm][tn][reg] + bias;
                }
        }
    }
}

// ================= CSR build =================
__global__ __launch_bounds__(256) void hist_kernel(
        const int* __restrict__ dst, int* __restrict__ cnt_work) {
    int e = blockIdx.x * blockDim.x + threadIdx.x;
    if (e < NEDGES) atomicAdd(cnt_work + dst[e], 1);
}

#define SCAN_T 1024
#define SCAN_CHUNK ((NNODES + SCAN_T - 1) / SCAN_T)
__global__ __launch_bounds__(SCAN_T) void scan_kernel(
        int* __restrict__ cnt_work, int* __restrict__ rowptr) {
    __shared__ int lds[SCAN_T];
    int t = threadIdx.x;
    int lo = t * SCAN_CHUNK;
    int hi = min(lo + SCAN_CHUNK, NNODES);
    int partial = 0;
    for (int i = lo; i < hi; ++i) partial += cnt_work[i];
    lds[t] = partial;
    __syncthreads();
    for (int off = 1; off < SCAN_T; off <<= 1) {
        int v = (t >= off) ? lds[t - off] : 0;
        __syncthreads();
        lds[t] += v;
        __syncthreads();
    }
    int running = lds[t] - partial;
    for (int i = lo; i < hi; ++i) {
        int c = cnt_work[i];
        rowptr[i] = running;
        cnt_work[i] = running;
        running += c;
    }
    if (t == SCAN_T - 1) rowptr[NNODES] = lds[SCAN_T - 1];
}

__global__ __launch_bounds__(256) void scatter_kernel(
        const int* __restrict__ src, const int* __restrict__ dst,
        int* __restrict__ cnt_work,
        int* __restrict__ eidx, int* __restrict__ esrc) {
    int e = blockIdx.x * blockDim.x + threadIdx.x;
    if (e >= NEDGES) return;
    int s = src[e];
    int pos = atomicAdd(cnt_work + dst[e], 1);
    eidx[pos] = e;
    esrc[pos] = s;
}

// ================= fused: scores + online softmax + aggregate + normalize =================
// one wave per node; lane l owns dims 2l,2l+1; head hh = l>>4.
// Raw per-edge scores stashed in LDS (cap 128 edges/node); deg>128 falls back
// to a recompute path (never taken at mean degree 16, but correct).
#define DEGCAP 128

__global__ __launch_bounds__(256) void node_fused_kernel(
        const ushort* __restrict__ el_bf, const float* __restrict__ er,
        const int* __restrict__ rowptr, const int* __restrict__ eidx,
        const int* __restrict__ esrc,
        const float* __restrict__ attn,
        float* __restrict__ out_feat, float* __restrict__ out_a) {
    __shared__ float sp[4][DEGCAP * NH];   // 2 KB per wave

    const int wv = threadIdx.x >> 6;
    const int n = blockIdx.x * 4 + wv;
    if (n >= NNODES) return;
    const int lane = threadIdx.x & 63;
    const int hh = lane >> 4;
    const int lo = rowptr[n], hi = rowptr[n + 1];
    const int deg = hi - lo;
    float* spw = sp[wv];

    const float2 rv = *(const float2*)(er + (size_t)n * HD + lane * 2);
    const float a0 = attn[lane * 2], a1 = attn[lane * 2 + 1];

    float m = -3.4e38f, lsum = 0.0f, acc0 = 0.0f, acc1 = 0.0f;

#define LOADU(var, j) \
    if ((j) < deg) { int s_ = esrc[lo + (j)]; \
        var = *(const ushort2*)(el_bf + (size_t)s_ * HD + lane * 2); }

#define PROC(u, j) \
    if ((j) < deg) { \
        float evx = bf2f(u.x), evy = bf2f(u.y); \
        if ((j) + 4 < deg) { int s_ = esrc[lo + (j) + 4]; \
            u = *(const ushort2*)(el_bf + (size_t)s_ * HD + lane * 2); } \
        float x0 = evx + rv.x; x0 = x0 > 0.f ? x0 : NEG * x0; \
        float x1 = evy + rv.y; x1 = x1 > 0.f ? x1 : NEG * x1; \
        float p = x0 * a0 + x1 * a1; \
        p += __shfl_xor(p, 1, 16); \
        p += __shfl_xor(p, 2, 16); \
        p += __shfl_xor(p, 4, 16); \
        p += __shfl_xor(p, 8, 16); \
        if ((lane & 15) == 0) spw[(j) * NH + hh] = p; \
        float mn = fmaxf(m, p); \
        float sc = __expf(m - mn); \
        float w  = __expf(p - mn); \
        lsum = lsum * sc + w; \
        acc0 = acc0 * sc + w * evx; \
        acc1 = acc1 * sc + w * evy; \
        m = mn; \
    }

    if (deg > 0 && deg <= DEGCAP) {
        ushort2 u0 = {0,0}, u1 = {0,0}, u2 = {0,0}, u3 = {0,0};
        LOADU(u0, 0) LOADU(u1, 1) LOADU(u2, 2) LOADU(u3, 3)
        for (int j0 = 0; j0 < deg; j0 += 4) {
            PROC(u0, j0)
            PROC(u1, j0 + 1)
            PROC(u2, j0 + 2)
            PROC(u3, j0 + 3)
        }
    } else if (deg > DEGCAP) {
        // fallback pass 1: online softmax only (no score stash)
        ushort2 u = {0,0};
        { int s_ = esrc[lo]; u = *(const ushort2*)(el_bf + (size_t)s_ * HD + lane * 2); }
        for (int i = lo; i < hi; ++i) {
            float evx = bf2f(u.x), evy = bf2f(u.y);
            if (i + 1 < hi) { int s_ = esrc[i + 1];
                u = *(const ushort2*)(el_bf + (size_t)s_ * HD + lane * 2); }
            float x0 = evx + rv.x; x0 = x0 > 0.f ? x0 : NEG * x0;
            float x1 = evy + rv.y; x1 = x1 > 0.f ? x1 : NEG * x1;
            float p = x0 * a0 + x1 * a1;
            p += __shfl_xor(p, 1, 16);
            p += __shfl_xor(p, 2, 16);
            p += __shfl_xor(p, 4, 16);
            p += __shfl_xor(p, 8, 16);
            float mn = fmaxf(m, p);
            float sc = __expf(m - mn);
            float w  = __expf(p - mn);
            lsum = lsum * sc + w;
            acc0 = acc0 * sc + w * evx;
            acc1 = acc1 * sc + w * evy;
            m = mn;
        }
    }

    // write aggregated features
    float2 o;
    if (deg == 0) { o.x = 0.0f; o.y = 0.0f; }
    else { float inv = 1.0f / lsum; o.x = acc0 * inv; o.y = acc1 * inv; }
    *(float2*)(out_feat + (size_t)n * HD + lane * 2) = o;

    if (deg == 0) return;

    // normalize + write attention weights
    float inv = 1.0f / lsum;
    if (deg <= DEGCAP) {
        // broadcast (m, inv) of head (lane&3) from its group (values uniform in group)
        float mh   = __shfl(m,   (lane & 3) << 4, 64);
        float invh = __shfl(inv, (lane & 3) << 4, 64);
        for (int j = (lane >> 2); j < deg; j += 16) {
            int e = eidx[lo + j];
            float p = spw[j * NH + (lane & 3)];
            out_a[(size_t)e * NH + (lane & 3)] = __expf(p - mh) * invh;
        }
    } else {
        // fallback pass 2: recompute scores and write a
        for (int i = lo; i < hi; ++i) {
            int s_ = esrc[i];
            ushort2 u = *(const ushort2*)(el_bf + (size_t)s_ * HD + lane * 2);
            float evx = bf2f(u.x), evy = bf2f(u.y);
            float x0 = evx + rv.x; x0 = x0 > 0.f ? x0 : NEG * x0;
            float x1 = evy + rv.y; x1 = x1 > 0.f ? x1 : NEG * x1;
            float p = x0 * a0 + x1 * a1;
            p += __shfl_xor(p, 1, 16);
            p += __shfl_xor(p, 2, 16);
            p += __shfl_xor(p, 4, 16);
            p += __shfl_xor(p, 8, 16);
            if ((lane & 15) == 0) {
                int e = eidx[i];
                out_a[(size_t)e * NH + hh] = __expf(p - m) * inv;
            }
        }
    }
#undef LOADU
#undef PROC
}

extern "C" void kernel_launch(void* const* d_in, const int* in_sizes, int n_in,
                              void* d_out, int out_size, void* d_ws, size_t ws_size,
                              hipStream_t stream) {
    const float* h    = (const float*)d_in[0];
    const int*   src  = (const int*)d_in[1];
    const int*   dst  = (const int*)d_in[2];
    const float* Wsrc = (const float*)d_in[3];
    const float* bsrc = (const float*)d_in[4];
    const float* Wdst = (const float*)d_in[5];
    const float* bdst = (const float*)d_in[6];
    const float* attn = (const float*)d_in[7];

    float* out_feat = (float*)d_out;                       // N*128
    float* out_a    = out_feat + (size_t)NNODES * HD;      // E*4

    // h_bf scratch lives in d_out (38.4 MB region, fully rewritten later):
    // conv_h -> gemm consume it before node_fused overwrites the region.
    ushort* h_bf = (ushort*)d_out;                         // N*256 bf16 = 25.6 MB

    // workspace layout (16B-aligned chunks)
    float*  er       = (float*)d_ws;                         // N*128 f32
    ushort* Wt       = (ushort*)(er + (size_t)NNODES * HD);  // 256*256 bf16
    ushort* el_bf    = Wt + 2 * HD * INDIM;                  // N*128 bf16
    int*    cnt_work = (int*)(el_bf + (size_t)NNODES * HD);  // N
    int*    eidx     = cnt_work + NNODES;                    // E
    int*    esrc     = eidx + NEDGES;                        // E
    int*    rowptr   = esrc + NEDGES;                        // N+1

    hipMemsetAsync(cnt_work, 0, NNODES * sizeof(int), stream);

    dim3 cwgrid(INDIM / 32, 256 / 32);
    conv_w_kernel<<<cwgrid, dim3(32, 8), 0, stream>>>(Wsrc, Wdst, Wt);

    conv_h_kernel<<<(NNODES * INDIM / 8 + 255) / 256, 256, 0, stream>>>(h, h_bf);

    dim3 ggrid(2, (NNODES + 127) / 128);
    gemm_mfma_kernel<<<ggrid, 256, 0, stream>>>(h_bf, Wt, bsrc, bdst, el_bf, er);

    hist_kernel<<<(NEDGES + 255) / 256, 256, 0, stream>>>(dst, cnt_work);
    scan_kernel<<<1, SCAN_T, 0, stream>>>(cnt_work, rowptr);
    scatter_kernel<<<(NEDGES + 255) / 256, 256, 0, stream>>>(src, dst, cnt_work, eidx, esrc);

    node_fused_kernel<<<(NNODES + 3) / 4, 256, 0, stream>>>(
        el_bf, er, rowptr, eidx, esrc, attn, out_feat, out_a);
}

// Round 6
// 323.840 us; speedup vs baseline: 3.5474x; 1.3029x over previous
//
#include <hip/hip_runtime.h>
#include <cstdint>
#include <cstddef>

#define NNODES 50000
#define NEDGES 800000
#define INDIM  256
#define HD     128   // H*D
#define NH     4
#define NEG    0.2f

#define SCAN_B ((NNODES + 255) / 256)   // 196 blocks

typedef __attribute__((ext_vector_type(8))) short   short8;   // 8 bf16 (4 VGPRs)
typedef __attribute__((ext_vector_type(8))) ushort  ushort8;
typedef __attribute__((ext_vector_type(4))) float   floatx4;

// f32 -> bf16 (round-to-nearest-even), raw bits
__device__ __forceinline__ ushort f2bf(float f) {
    unsigned u = __float_as_uint(f);
    unsigned r = u + 0x7fffu + ((u >> 16) & 1u);
    return (ushort)(r >> 16);
}
__device__ __forceinline__ float bf2f(ushort u) {
    return __uint_as_float(((unsigned)u) << 16);
}

// ================= h convert: f32 -> bf16, 8 elems/thread =================
__global__ __launch_bounds__(256) void conv_h_kernel(
        const float* __restrict__ h, ushort* __restrict__ h_bf) {
    int idx = blockIdx.x * 256 + threadIdx.x;     // chunk of 8
    const int total = NNODES * INDIM / 8;         // 1.6M
    if (idx >= total) return;
    const float* p = h + (size_t)idx * 8;
    float4 v0 = *(const float4*)p;
    float4 v1 = *(const float4*)(p + 4);
    ushort8 o;
    o[0] = f2bf(v0.x); o[1] = f2bf(v0.y); o[2] = f2bf(v0.z); o[3] = f2bf(v0.w);
    o[4] = f2bf(v1.x); o[5] = f2bf(v1.y); o[6] = f2bf(v1.z); o[7] = f2bf(v1.w);
    *(ushort8*)(h_bf + (size_t)idx * 8) = o;
}

// ================= W convert+transpose (LDS-tiled): Wt[n][k] bf16 =================
__global__ __launch_bounds__(256) void conv_w_kernel(
        const float* __restrict__ Wsrc, const float* __restrict__ Wdst,
        ushort* __restrict__ Wt) {
    __shared__ float t[32][33];
    int kb = blockIdx.x * 32, nb = blockIdx.y * 32;
    for (int i = threadIdx.y; i < 32; i += 8) {
        int k = kb + i, n = nb + threadIdx.x;
        float v = (n < HD) ? Wsrc[(size_t)k * HD + n] : Wdst[(size_t)k * HD + (n - HD)];
        t[i][threadIdx.x] = v;
    }
    __syncthreads();
    for (int i = threadIdx.y; i < 32; i += 8) {
        int n = nb + i, k = kb + threadIdx.x;
        Wt[(size_t)n * INDIM + k] = f2bf(t[threadIdx.x][i]);
    }
}

// LDS chunk swizzle: conflict-free staging writes + fragment reads
__device__ __forceinline__ int swz(int c) { return c ^ ((c >> 4) & 7); }

// ================= MFMA GEMM =================
// grid.x==0 -> el (bf16 out), grid.x==1 -> er (f32 out). 128 rows x 128 cols per block.
__global__ __launch_bounds__(256) void gemm_mfma_kernel(
        const ushort* __restrict__ h_bf, const ushort* __restrict__ Wt,
        const float* __restrict__ bsrc, const float* __restrict__ bdst,
        ushort* __restrict__ el_bf, float* __restrict__ er) {
    __shared__ ushort As[512 * 8];  // 512 fragment-chunks of 8 bf16
    __shared__ ushort Bs[512 * 8];

    const int tid  = threadIdx.x;
    const int wave = tid >> 6, lane = tid & 63;
    const int row0 = blockIdx.y * 128;
    const int col0 = blockIdx.x * 128;   // 0 -> el, 128 -> er
    const int l15  = lane & 15, quad = lane >> 4;

    floatx4 acc[2][8];
#pragma unroll
    for (int i = 0; i < 2; ++i)
#pragma unroll
        for (int j = 0; j < 8; ++j) acc[i][j] = (floatx4){0.f, 0.f, 0.f, 0.f};

    for (int kk = 0; kk < INDIM; kk += 32) {
#pragma unroll
        for (int it = 0; it < 2; ++it) {
            int idx = tid + it * 256;    // 0..511
            int r = idx >> 2;            // 0..127
            int kq = idx & 3;            // k-quad (8 elems)
            int c = (r >> 4) * 64 + kq * 16 + (r & 15);
            // ---- A: pre-converted bf16 ----
            int grow = row0 + r;
            ushort8 aw = (ushort8){0,0,0,0,0,0,0,0};
            if (grow < NNODES)
                aw = *(const ushort8*)(h_bf + (size_t)grow * INDIM + kk + kq * 8);
            *(ushort8*)(As + swz(c) * 8) = aw;
            // ---- B ----
            ushort8 bw = *(const ushort8*)(Wt + (size_t)(col0 + r) * INDIM + kk + kq * 8);
            *(ushort8*)(Bs + swz(c) * 8) = bw;
        }
        __syncthreads();

        short8 af[2], bf[8];
#pragma unroll
        for (int tm = 0; tm < 2; ++tm) {
            int c = (wave * 2 + tm) * 64 + quad * 16 + l15;
            af[tm] = *(const short8*)(As + swz(c) * 8);
        }
#pragma unroll
        for (int tn = 0; tn < 8; ++tn) {
            int c = tn * 64 + quad * 16 + l15;
            bf[tn] = *(const short8*)(Bs + swz(c) * 8);
        }
#pragma unroll
        for (int tm = 0; tm < 2; ++tm)
#pragma unroll
            for (int tn = 0; tn < 8; ++tn)
                acc[tm][tn] = __builtin_amdgcn_mfma_f32_16x16x32_bf16(
                    af[tm], bf[tn], acc[tm][tn], 0, 0, 0);
        __syncthreads();
    }

    // epilogue: C/D layout col=lane&15, row=quad*4+reg
    if (col0 == 0) {
#pragma unroll
        for (int tn = 0; tn < 8; ++tn) {
            int col = tn * 16 + l15;
            float bias = bsrc[col];
#pragma unroll
            for (int tm = 0; tm < 2; ++tm)
#pragma unroll
                for (int reg = 0; reg < 4; ++reg) {
                    int row = row0 + wave * 32 + tm * 16 + quad * 4 + reg;
                    if (row < NNODES)
                        el_bf[(size_t)row * HD + col] = f2bf(acc[tm][tn][reg] + bias);
                }
        }
    } else {
#pragma unroll
        for (int tn = 0; tn < 8; ++tn) {
            int col = tn * 16 + l15;
            float bias = bdst[col];
#pragma unroll
            for (int tm = 0; tm < 2; ++tm)
#pragma unroll
                for (int reg = 0; reg < 4; ++reg) {
                    int row = row0 + wave * 32 + tm * 16 + quad * 4 + reg;
                    if (row < NNODES)
                        er[(size_t)row * HD + col] = acc[tm][tn][reg] + bias;
                }
        }
    }
}

// ================= CSR build =================
__global__ __launch_bounds__(256) void hist_kernel(
        const int* __restrict__ dst, int* __restrict__ cnt_work) {
    int e = blockIdx.x * blockDim.x + threadIdx.x;
    if (e < NEDGES) atomicAdd(cnt_work + dst[e], 1);
}

// ---- 3-phase multi-block scan ----
// Phase A: per-block reduce of 256 counts -> partials[SCAN_B]
__global__ __launch_bounds__(256) void scan_partial_kernel(
        const int* __restrict__ cnt, int* __restrict__ partials) {
    __shared__ int lds[256];
    int i = blockIdx.x * 256 + threadIdx.x;
    lds[threadIdx.x] = (i < NNODES) ? cnt[i] : 0;
    __syncthreads();
    for (int off = 128; off > 0; off >>= 1) {
        if (threadIdx.x < off) lds[threadIdx.x] += lds[threadIdx.x + off];
        __syncthreads();
    }
    if (threadIdx.x == 0) partials[blockIdx.x] = lds[0];
}

// Phase B: single 256-thread block: exclusive scan of partials in place + total
__global__ __launch_bounds__(256) void scan_offsets_kernel(
        int* __restrict__ partials, int* __restrict__ rowptr) {
    __shared__ int lds[256];
    int t = threadIdx.x;
    int v = (t < SCAN_B) ? partials[t] : 0;
    lds[t] = v;
    __syncthreads();
    for (int off = 1; off < 256; off <<= 1) {
        int u = (t >= off) ? lds[t - off] : 0;
        __syncthreads();
        lds[t] += u;
        __syncthreads();
    }
    if (t < SCAN_B) partials[t] = lds[t] - v;      // exclusive
    if (t == 255) rowptr[NNODES] = lds[255];       // total
}

// Phase C: block-local exclusive scan + offset -> rowptr, cnt_work := row start
__global__ __launch_bounds__(256) void scan_final_kernel(
        int* __restrict__ cnt_work, const int* __restrict__ partials,
        int* __restrict__ rowptr) {
    __shared__ int lds[256];
    int i = blockIdx.x * 256 + threadIdx.x;
    int t = threadIdx.x;
    int v = (i < NNODES) ? cnt_work[i] : 0;
    lds[t] = v;
    __syncthreads();
    for (int off = 1; off < 256; off <<= 1) {
        int u = (t >= off) ? lds[t - off] : 0;
        __syncthreads();
        lds[t] += u;
        __syncthreads();
    }
    if (i < NNODES) {
        int start = partials[blockIdx.x] + lds[t] - v;
        rowptr[i] = start;
        cnt_work[i] = start;
    }
}

__global__ __launch_bounds__(256) void scatter_kernel(
        const int* __restrict__ src, const int* __restrict__ dst,
        int* __restrict__ cnt_work,
        int* __restrict__ eidx, int* __restrict__ esrc) {
    int e = blockIdx.x * blockDim.x + threadIdx.x;
    if (e >= NEDGES) return;
    int s = src[e];
    int pos = atomicAdd(cnt_work + dst[e], 1);
    eidx[pos] = e;
    esrc[pos] = s;
}

// ================= fused: scores + online softmax + aggregate + normalize =================
// one wave per node; lane l owns dims 2l,2l+1; head hh = l>>4.
// Raw per-edge scores stashed in LDS (cap 128 edges/node); deg>128 falls back
// to a recompute path (never taken at mean degree 16, but correct).
#define DEGCAP 128

__global__ __launch_bounds__(256) void node_fused_kernel(
        const ushort* __restrict__ el_bf, const float* __restrict__ er,
        const int* __restrict__ rowptr, const int* __restrict__ eidx,
        const int* __restrict__ esrc,
        const float* __restrict__ attn,
        float* __restrict__ out_feat, float* __restrict__ out_a) {
    __shared__ float sp[4][DEGCAP * NH];   // 2 KB per wave

    const int wv = threadIdx.x >> 6;
    const int n = blockIdx.x * 4 + wv;
    if (n >= NNODES) return;
    const int lane = threadIdx.x & 63;
    const int hh = lane >> 4;
    const int lo = rowptr[n], hi = rowptr[n + 1];
    const int deg = hi - lo;
    float* spw = sp[wv];

    const float2 rv = *(const float2*)(er + (size_t)n * HD + lane * 2);
    const float a0 = attn[lane * 2], a1 = attn[lane * 2 + 1];

    float m = -3.4e38f, lsum = 0.0f, acc0 = 0.0f, acc1 = 0.0f;

#define LOADU(var, j) \
    if ((j) < deg) { int s_ = esrc[lo + (j)]; \
        var = *(const ushort2*)(el_bf + (size_t)s_ * HD + lane * 2); }

#define PROC(u, j) \
    if ((j) < deg) { \
        float evx = bf2f(u.x), evy = bf2f(u.y); \
        if ((j) + 4 < deg) { int s_ = esrc[lo + (j) + 4]; \
            u = *(const ushort2*)(el_bf + (size_t)s_ * HD + lane * 2); } \
        float x0 = evx + rv.x; x0 = x0 > 0.f ? x0 : NEG * x0; \
        float x1 = evy + rv.y; x1 = x1 > 0.f ? x1 : NEG * x1; \
        float p = x0 * a0 + x1 * a1; \
        p += __shfl_xor(p, 1, 16); \
        p += __shfl_xor(p, 2, 16); \
        p += __shfl_xor(p, 4, 16); \
        p += __shfl_xor(p, 8, 16); \
        if ((lane & 15) == 0) spw[(j) * NH + hh] = p; \
        float mn = fmaxf(m, p); \
        float sc = __expf(m - mn); \
        float w  = __expf(p - mn); \
        lsum = lsum * sc + w; \
        acc0 = acc0 * sc + w * evx; \
        acc1 = acc1 * sc + w * evy; \
        m = mn; \
    }

    if (deg > 0 && deg <= DEGCAP) {
        ushort2 u0 = {0,0}, u1 = {0,0}, u2 = {0,0}, u3 = {0,0};
        LOADU(u0, 0) LOADU(u1, 1) LOADU(u2, 2) LOADU(u3, 3)
        for (int j0 = 0; j0 < deg; j0 += 4) {
            PROC(u0, j0)
            PROC(u1, j0 + 1)
            PROC(u2, j0 + 2)
            PROC(u3, j0 + 3)
        }
    } else if (deg > DEGCAP) {
        // fallback pass 1: online softmax only (no score stash)
        ushort2 u = {0,0};
        { int s_ = esrc[lo]; u = *(const ushort2*)(el_bf + (size_t)s_ * HD + lane * 2); }
        for (int i = lo; i < hi; ++i) {
            float evx = bf2f(u.x), evy = bf2f(u.y);
            if (i + 1 < hi) { int s_ = esrc[i + 1];
                u = *(const ushort2*)(el_bf + (size_t)s_ * HD + lane * 2); }
            float x0 = evx + rv.x; x0 = x0 > 0.f ? x0 : NEG * x0;
            float x1 = evy + rv.y; x1 = x1 > 0.f ? x1 : NEG * x1;
            float p = x0 * a0 + x1 * a1;
            p += __shfl_xor(p, 1, 16);
            p += __shfl_xor(p, 2, 16);
            p += __shfl_xor(p, 4, 16);
            p += __shfl_xor(p, 8, 16);
            float mn = fmaxf(m, p);
            float sc = __expf(m - mn);
            float w  = __expf(p - mn);
            lsum = lsum * sc + w;
            acc0 = acc0 * sc + w * evx;
            acc1 = acc1 * sc + w * evy;
            m = mn;
        }
    }

    // write aggregated features
    float2 o;
    if (deg == 0) { o.x = 0.0f; o.y = 0.0f; }
    else { float inv = 1.0f / lsum; o.x = acc0 * inv; o.y = acc1 * inv; }
    *(float2*)(out_feat + (size_t)n * HD + lane * 2) = o;

    if (deg == 0) return;

    // normalize + write attention weights
    float inv = 1.0f / lsum;
    if (deg <= DEGCAP) {
        // broadcast (m, inv) of head (lane&3) from its group (values uniform in group)
        float mh   = __shfl(m,   (lane & 3) << 4, 64);
        float invh = __shfl(inv, (lane & 3) << 4, 64);
        for (int j = (lane >> 2); j < deg; j += 16) {
            int e = eidx[lo + j];
            float p = spw[j * NH + (lane & 3)];
            out_a[(size_t)e * NH + (lane & 3)] = __expf(p - mh) * invh;
        }
    } else {
        // fallback pass 2: recompute scores and write a
        for (int i = lo; i < hi; ++i) {
            int s_ = esrc[i];
            ushort2 u = *(const ushort2*)(el_bf + (size_t)s_ * HD + lane * 2);
            float evx = bf2f(u.x), evy = bf2f(u.y);
            float x0 = evx + rv.x; x0 = x0 > 0.f ? x0 : NEG * x0;
            float x1 = evy + rv.y; x1 = x1 > 0.f ? x1 : NEG * x1;
            float p = x0 * a0 + x1 * a1;
            p += __shfl_xor(p, 1, 16);
            p += __shfl_xor(p, 2, 16);
            p += __shfl_xor(p, 4, 16);
            p += __shfl_xor(p, 8, 16);
            if ((lane & 15) == 0) {
                int e = eidx[i];
                out_a[(size_t)e * NH + hh] = __expf(p - m) * inv;
            }
        }
    }
#undef LOADU
#undef PROC
}

extern "C" void kernel_launch(void* const* d_in, const int* in_sizes, int n_in,
                              void* d_out, int out_size, void* d_ws, size_t ws_size,
                              hipStream_t stream) {
    const float* h    = (const float*)d_in[0];
    const int*   src  = (const int*)d_in[1];
    const int*   dst  = (const int*)d_in[2];
    const float* Wsrc = (const float*)d_in[3];
    const float* bsrc = (const float*)d_in[4];
    const float* Wdst = (const float*)d_in[5];
    const float* bdst = (const float*)d_in[6];
    const float* attn = (const float*)d_in[7];

    float* out_feat = (float*)d_out;                       // N*128
    float* out_a    = out_feat + (size_t)NNODES * HD;      // E*4

    // h_bf scratch lives in d_out (38.4 MB region, fully rewritten later):
    // conv_h -> gemm consume it before node_fused overwrites the region.
    ushort* h_bf = (ushort*)d_out;                         // N*256 bf16 = 25.6 MB

    // workspace layout (16B-aligned chunks)
    float*  er       = (float*)d_ws;                         // N*128 f32
    ushort* Wt       = (ushort*)(er + (size_t)NNODES * HD);  // 256*256 bf16
    ushort* el_bf    = Wt + 2 * HD * INDIM;                  // N*128 bf16
    int*    cnt_work = (int*)(el_bf + (size_t)NNODES * HD);  // N
    int*    eidx     = cnt_work + NNODES;                    // E
    int*    esrc     = eidx + NEDGES;                        // E
    int*    rowptr   = esrc + NEDGES;                        // N+1
    int*    partials = rowptr + NNODES + 1;                  // SCAN_B

    hipMemsetAsync(cnt_work, 0, NNODES * sizeof(int), stream);

    dim3 cwgrid(INDIM / 32, 256 / 32);
    conv_w_kernel<<<cwgrid, dim3(32, 8), 0, stream>>>(Wsrc, Wdst, Wt);

    conv_h_kernel<<<(NNODES * INDIM / 8 + 255) / 256, 256, 0, stream>>>(h, h_bf);

    dim3 ggrid(2, (NNODES + 127) / 128);
    gemm_mfma_kernel<<<ggrid, 256, 0, stream>>>(h_bf, Wt, bsrc, bdst, el_bf, er);

    hist_kernel<<<(NEDGES + 255) / 256, 256, 0, stream>>>(dst, cnt_work);
    scan_partial_kernel<<<SCAN_B, 256, 0, stream>>>(cnt_work, partials);
    scan_offsets_kernel<<<1, 256, 0, stream>>>(partials, rowptr);
    scan_final_kernel<<<SCAN_B, 256, 0, stream>>>(cnt_work, partials, rowptr);
    scatter_kernel<<<(NEDGES + 255) / 256, 256, 0, stream>>>(src, dst, cnt_work, eidx, esrc);

    node_fused_kernel<<<(NNODES + 3) / 4, 256, 0, stream>>>(
        el_bf, er, rowptr, eidx, esrc, attn, out_feat, out_a);
}